// Round 17
// baseline (111.710 us; speedup 1.0000x reference)
//
#include <hip/hip_runtime.h>
#include <math.h>

typedef __attribute__((ext_vector_type(8))) short short8;
typedef __attribute__((ext_vector_type(4))) float f32x4;

#define SEQ 2048
#define NB  32

__device__ __forceinline__ unsigned short f2bf(float f) {
    unsigned u = __float_as_uint(f);
    u = (u + 0x7FFFu + ((u >> 16) & 1u)) >> 16;   // RNE
    return (unsigned short)u;
}

// async global->LDS, 16B per lane; LDS dest = wave-uniform base + lane*16
__device__ __forceinline__ void gload16(const unsigned short* g, unsigned short* l) {
    __builtin_amdgcn_global_load_lds(
        (__attribute__((address_space(1))) void*)(void*)(g),
        (__attribute__((address_space(3))) void*)(l), 16, 0, 0);
}

// ---------------------------------------------------------------------------
// fp32 -> bf16 (RNE): 5 tensors in ONE dispatch. blockIdx.y selects the job.
// ---------------------------------------------------------------------------
__global__ __launch_bounds__(256) void cvt_all(const float* __restrict__ x,
                                               const float* __restrict__ w0,
                                               const float* __restrict__ w1,
                                               const float* __restrict__ w2,
                                               const float* __restrict__ w3,
                                               unsigned short* __restrict__ ox,
                                               unsigned short* __restrict__ o0,
                                               unsigned short* __restrict__ o1,
                                               unsigned short* __restrict__ o2,
                                               unsigned short* __restrict__ o3) {
    const int which = blockIdx.y;
    const float* in = (which == 0) ? x : (which == 1) ? w0 : (which == 2) ? w1
                       : (which == 3) ? w2 : w3;
    unsigned short* out = (which == 0) ? ox : (which == 1) ? o0 : (which == 2) ? o1
                          : (which == 3) ? o2 : o3;
    const int n8 = (which == 0) ? 524288 : 131072;
    int i = blockIdx.x * 256 + threadIdx.x;
    const int stride = gridDim.x * 256;
    for (; i < n8; i += stride) {
        const float4 a = ((const float4*)in)[i * 2];
        const float4 b = ((const float4*)in)[i * 2 + 1];
        uint4 o;
        o.x = f2bf(a.x) | ((unsigned)f2bf(a.y) << 16);
        o.y = f2bf(a.z) | ((unsigned)f2bf(a.w) << 16);
        o.z = f2bf(b.x) | ((unsigned)f2bf(b.y) << 16);
        o.w = f2bf(b.z) | ((unsigned)f2bf(b.w) << 16);
        ((uint4*)out)[i] = o;
    }
}

// ---------------------------------------------------------------------------
// QKV bf16 MFMA GEMM — PERMANENTLY FROZEN (round-11/15 structure, 43.6us,
// 592 TF = the 2-phase family floor per m233). Do not touch.
// BN=128: 4 waves 2x2 (64x64, MI=4), grid (24, 32), which=bx>>3.
// NOTE (round-3 lesson): head split is a .view — head h = GEMM ROWS.
// ---------------------------------------------------------------------------
template <int BF16OUT, int BN>
__global__ __launch_bounds__(256) void gemm_bt(const unsigned short* __restrict__ A,
                                               const unsigned short* __restrict__ Wall,
                                               const float* __restrict__ b0,
                                               const float* __restrict__ b1,
                                               const float* __restrict__ b2,
                                               unsigned short* __restrict__ outb,
                                               float* __restrict__ outf) {
    constexpr int MI = (BN == 128) ? 4 : 2;
    constexpr int NI = 4;
    __shared__ __align__(16) unsigned short SMEM[2 * 128 * 32 + 2 * BN * 32];
    unsigned short* As0 = SMEM;
    unsigned short* As1 = SMEM + 128 * 32;
    unsigned short* Bs0 = SMEM + 2 * 128 * 32;
    unsigned short* Bs1 = SMEM + 2 * 128 * 32 + BN * 32;

    const int t = threadIdx.x;
    const int w = t >> 6, l = t & 63;
    const int bx = blockIdx.x;
    const int which = (BN == 128) ? (bx >> 3) : 0;
    const int n0 = (BN == 128) ? (bx & 7) * 128 : bx * 64;
    const int m0 = blockIdx.y * 128;
    const unsigned short* W = Wall + (size_t)which * (1024ull * 1024);
    const float* bias = (which == 0) ? b0 : (which == 1) ? b1 : b2;

    const int wr = (BN == 128) ? (w >> 1) * 64 : w * 32;
    const int wc = (BN == 128) ? (w & 1) * 64 : 0;

    f32x4 acc[MI][NI];
#pragma unroll
    for (int i = 0; i < MI; ++i)
#pragma unroll
        for (int j = 0; j < NI; ++j) acc[i][j] = f32x4{0.f, 0.f, 0.f, 0.f};

    const unsigned short* Ag = A + (size_t)(m0 + w * 32 + (l >> 2)) * 1024 + (l & 3) * 8;
    const unsigned short* Wg =
        W + (size_t)(n0 + ((BN == 128) ? w * 32 : w * 16) + (l >> 2)) * 1024 + (l & 3) * 8;

    auto STAGE = [&](unsigned short* Asb, unsigned short* Bsb, int k0) {
        gload16(Ag + k0, Asb + w * 1024);
        gload16(Ag + k0 + 16 * 1024, Asb + w * 1024 + 512);
        gload16(Wg + k0, Bsb + ((BN == 128) ? w * 1024 : w * 512));
        if (BN == 128) gload16(Wg + k0 + 16 * 1024, Bsb + w * 1024 + 512);
    };
    auto COMPUTE = [&](const unsigned short* Asb, const unsigned short* Bsb) {
        short8 af[MI], bfr[NI];
#pragma unroll
        for (int mi = 0; mi < MI; ++mi)
            af[mi] = *(const short8*)&Asb[(wr + mi * 16 + (l & 15)) * 32 + (l >> 4) * 8];
#pragma unroll
        for (int ni = 0; ni < NI; ++ni)
            bfr[ni] = *(const short8*)&Bsb[(wc + ni * 16 + (l & 15)) * 32 + (l >> 4) * 8];
#pragma unroll
        for (int mi = 0; mi < MI; ++mi)
#pragma unroll
            for (int ni = 0; ni < NI; ++ni)
                acc[mi][ni] = __builtin_amdgcn_mfma_f32_16x16x32_bf16(af[mi], bfr[ni],
                                                                      acc[mi][ni], 0, 0, 0);
    };
#define WAITV_INFLIGHT()                                                  \
    do {                                                                  \
        if constexpr (BN == 128)                                          \
            asm volatile("s_waitcnt vmcnt(4)" ::: "memory");              \
        else                                                              \
            asm volatile("s_waitcnt vmcnt(3)" ::: "memory");              \
        __builtin_amdgcn_sched_barrier(0);                                \
    } while (0)
#define BAR()                                                             \
    do {                                                                  \
        __builtin_amdgcn_s_barrier();                                     \
        __builtin_amdgcn_sched_barrier(0);                                \
    } while (0)
#define READS_DONE_BAR()                                                  \
    do {                                                                  \
        asm volatile("s_waitcnt lgkmcnt(0)" ::: "memory");                \
        __builtin_amdgcn_sched_barrier(0);                                \
        __builtin_amdgcn_s_barrier();                                     \
        __builtin_amdgcn_sched_barrier(0);                                \
    } while (0)

    STAGE(As0, Bs0, 0);
#pragma unroll 1
    for (int kt2 = 0; kt2 < 16; ++kt2) {
        STAGE(As1, Bs1, (kt2 * 2 + 1) * 32);
        WAITV_INFLIGHT();
        BAR();
        COMPUTE(As0, Bs0);
        READS_DONE_BAR();

        if (kt2 < 15) {
            STAGE(As0, Bs0, (kt2 * 2 + 2) * 32);
            WAITV_INFLIGHT();
        } else {
            asm volatile("s_waitcnt vmcnt(0)" ::: "memory");
            __builtin_amdgcn_sched_barrier(0);
        }
        BAR();
        COMPUTE(As1, Bs1);
        if (kt2 < 15) READS_DONE_BAR();
    }
#undef WAITV_INFLIGHT
#undef BAR
#undef READS_DONE_BAR

    __syncthreads();
    const int g = l >> 4, c = l & 15;
    if constexpr (BF16OUT) {
        unsigned short* eb = SMEM + w * (32 * 72);
        unsigned short* outw = outb + (size_t)which * (4096ull * 1024);
        const int r1 = l >> 1, hh = (l & 1) * 32;
#pragma unroll
        for (int half = 0; half < 2; ++half) {
#pragma unroll
            for (int ni = 0; ni < NI; ++ni) {
                const float bv = bias[n0 + wc + ni * 16 + c];
#pragma unroll
                for (int mi2 = 0; mi2 < 2; ++mi2)
#pragma unroll
                    for (int j = 0; j < 4; ++j)
                        eb[(mi2 * 16 + g * 4 + j) * 72 + ni * 16 + c] =
                            f2bf(acc[half * 2 + mi2][ni][j] + bv);
            }
            asm volatile("s_waitcnt lgkmcnt(0)" ::: "memory");
            __builtin_amdgcn_sched_barrier(0);
            const unsigned short* src = eb + r1 * 72 + hh;
            unsigned short* dst =
                &outw[(size_t)(m0 + wr + half * 32 + r1) * 1024 + n0 + wc + hh];
#pragma unroll
            for (int q = 0; q < 4; ++q)
                *(uint4*)(dst + q * 8) = *(const uint4*)(src + q * 8);
            asm volatile("s_waitcnt lgkmcnt(0)" ::: "memory");
            __builtin_amdgcn_sched_barrier(0);
        }
    } else {
        float* ef = (float*)SMEM + w * (16 * 68);
        const int r2 = l >> 2, qq = (l & 3) * 16;
#pragma unroll
        for (int mi = 0; mi < MI; ++mi) {
#pragma unroll
            for (int ni = 0; ni < NI; ++ni) {
                const float bv = bias[n0 + wc + ni * 16 + c];
#pragma unroll
                for (int j = 0; j < 4; ++j)
                    ef[(g * 4 + j) * 68 + ni * 16 + c] = acc[mi][ni][j] + bv;
            }
            asm volatile("s_waitcnt lgkmcnt(0)" ::: "memory");
            __builtin_amdgcn_sched_barrier(0);
            const float* srcf = ef + r2 * 68 + qq;
            float* dstf = &outf[(size_t)(m0 + wr + mi * 16 + r2) * 1024 + n0 + wc + qq];
#pragma unroll
            for (int q = 0; q < 4; ++q)
                *(float4*)(dstf + q * 4) = *(const float4*)(srcf + q * 4);
            asm volatile("s_waitcnt lgkmcnt(0)" ::: "memory");
            __builtin_amdgcn_sched_barrier(0);
        }
    }
}

// ---------------------------------------------------------------------------
// O-projection GEMM — round-17: SPLIT-K=2 on top of the round-16 BK=64
// swizzled loop. grid (16,32,2): blockIdx.z selects K-half [kz*512, +512) =
// 8 K-steps per block (halves the serial stall chain; 1024 wgs, LDS 48KB ->
// 3 blocks/CU resident for stall hiding). Each half atomicAdd's into d_out.
// Determinism: d_out is zeroed each launch (hipMemsetAsync) and each element
// gets exactly TWO fp32 contributions — (0+a)+b == (0+b)+a bitwise, so the
// atomic ordering is value-irrelevant. Bias added by kz==0 only.
// Epilogue: direct dword atomics (lanes c=0..15 -> consecutive addresses).
// ---------------------------------------------------------------------------
__global__ __launch_bounds__(256) void gemm_obt_sk(const unsigned short* __restrict__ A,
                                                   const unsigned short* __restrict__ W,
                                                   const float* __restrict__ bias,
                                                   float* __restrict__ outf) {
    constexpr int MI = 2, NI = 4;
    __shared__ __align__(16) unsigned short SMEM[2 * (128 + 64) * 64];
    unsigned short* As0 = SMEM;                    // [128][64]
    unsigned short* As1 = SMEM + 128 * 64;
    unsigned short* Bs0 = SMEM + 2 * 128 * 64;     // [64][64]
    unsigned short* Bs1 = SMEM + 2 * 128 * 64 + 64 * 64;

    const int t = threadIdx.x;
    const int w = t >> 6, l = t & 63;
    const int n0 = blockIdx.x * 64;
    const int m0 = blockIdx.y * 128;
    const int kz = blockIdx.z;
    const int kbase = kz * 512;                    // shorts (K elements)

    const int wr = w * 32, wc = 0;

    f32x4 acc[MI][NI];
#pragma unroll
    for (int i = 0; i < MI; ++i)
#pragma unroll
        for (int j = 0; j < NI; ++j) acc[i][j] = f32x4{0.f, 0.f, 0.f, 0.f};

    // staging: lane l covers row (l>>3), global col-short ((l&7)^(l>>3))*8
    // (XOR bakes the T2 swizzle into the linear gload_lds write; proven r16)
    const int scol = ((l & 7) ^ (l >> 3)) * 8;
    const unsigned short* Ag = A + (size_t)(m0 + w * 32 + (l >> 3)) * 1024 + scol;
    const unsigned short* Wg = W + (size_t)(n0 + w * 16 + (l >> 3)) * 1024 + scol;

    auto STAGE = [&](unsigned short* Asb, unsigned short* Bsb, int k0) {
        gload16(Ag + k0, Asb + (w * 32) * 64);
        gload16(Ag + k0 + 8 * 1024, Asb + (w * 32 + 8) * 64);
        gload16(Ag + k0 + 16 * 1024, Asb + (w * 32 + 16) * 64);
        gload16(Ag + k0 + 24 * 1024, Asb + (w * 32 + 24) * 64);
        gload16(Wg + k0, Bsb + (w * 16) * 64);
        gload16(Wg + k0 + 8 * 1024, Bsb + (w * 16 + 8) * 64);
    };
    auto COMPUTE = [&](const unsigned short* Asb, const unsigned short* Bsb) {
#pragma unroll
        for (int kk = 0; kk < 2; ++kk) {
            short8 af[MI], bfr[NI];
#pragma unroll
            for (int mi = 0; mi < MI; ++mi) {
                const int r = wr + mi * 16 + (l & 15);
                const int slot = (kk * 4 + (l >> 4)) ^ (r & 7);
                af[mi] = *(const short8*)&Asb[r * 64 + slot * 8];
            }
#pragma unroll
            for (int ni = 0; ni < NI; ++ni) {
                const int r = wc + ni * 16 + (l & 15);
                const int slot = (kk * 4 + (l >> 4)) ^ (r & 7);
                bfr[ni] = *(const short8*)&Bsb[r * 64 + slot * 8];
            }
#pragma unroll
            for (int mi = 0; mi < MI; ++mi)
#pragma unroll
                for (int ni = 0; ni < NI; ++ni)
                    acc[mi][ni] = __builtin_amdgcn_mfma_f32_16x16x32_bf16(
                        af[mi], bfr[ni], acc[mi][ni], 0, 0, 0);
        }
    };
#define WV6()                                                             \
    do {                                                                  \
        asm volatile("s_waitcnt vmcnt(6)" ::: "memory");                  \
        __builtin_amdgcn_sched_barrier(0);                                \
    } while (0)
#define BAR()                                                             \
    do {                                                                  \
        __builtin_amdgcn_s_barrier();                                     \
        __builtin_amdgcn_sched_barrier(0);                                \
    } while (0)
#define READS_DONE_BAR()                                                  \
    do {                                                                  \
        asm volatile("s_waitcnt lgkmcnt(0)" ::: "memory");                \
        __builtin_amdgcn_sched_barrier(0);                                \
        __builtin_amdgcn_s_barrier();                                     \
        __builtin_amdgcn_sched_barrier(0);                                \
    } while (0)

    STAGE(As0, Bs0, kbase);
#pragma unroll 1
    for (int kt2 = 0; kt2 < 4; ++kt2) {          // 8 K-steps of 64 per half
        STAGE(As1, Bs1, kbase + (kt2 * 2 + 1) * 64);
        WV6();
        BAR();
        COMPUTE(As0, Bs0);
        READS_DONE_BAR();

        if (kt2 < 3) {
            STAGE(As0, Bs0, kbase + (kt2 * 2 + 2) * 64);
            WV6();
        } else {
            asm volatile("s_waitcnt vmcnt(0)" ::: "memory");
            __builtin_amdgcn_sched_barrier(0);
        }
        BAR();
        COMPUTE(As1, Bs1);
        if (kt2 < 3) READS_DONE_BAR();
    }
#undef WV6
#undef BAR
#undef READS_DONE_BAR

    // direct atomic epilogue (dword atomics, consecutive addresses per group)
    const int g = l >> 4, c = l & 15;
#pragma unroll
    for (int ni = 0; ni < NI; ++ni) {
        const int n = n0 + wc + ni * 16 + c;
        const float bv = (kz == 0) ? bias[n] : 0.f;
#pragma unroll
        for (int mi = 0; mi < MI; ++mi)
#pragma unroll
            for (int j = 0; j < 4; ++j) {
                const size_t m = (size_t)(m0 + wr + mi * 16 + g * 4 + j);
                atomicAdd(&outf[m * 1024 + n], acc[mi][ni][j] + bv);
            }
    }
}

// ---------------------------------------------------------------------------
// BigBird MFMA attention (bf16 in, bf16 out), swapped-QK^T flash style.
// grid (32 qblk, 16 h, 2 b), 256 thr = 4 waves; wave w owns 16 q-rows.
// S^T = K·Q^T -> softmax in-lane + 2 shfl_xor;  O^T = V^T·P^T.
// V transposed during LDS staging; T14 prefetch-next-active-block (round-15).
// ---------------------------------------------------------------------------
__global__ __launch_bounds__(256) void attn_mfma(const unsigned short* __restrict__ qb_,
                                                 const unsigned short* __restrict__ kb_,
                                                 const unsigned short* __restrict__ vb_,
                                                 const int* __restrict__ srcb,
                                                 const int* __restrict__ tgtb,
                                                 unsigned short* __restrict__ outb) {
    __shared__ __align__(16) unsigned short Ks[64 * 72];
    __shared__ __align__(16) unsigned short Vs[64 * 72];   // V^T tile [d][key]
    __shared__ __align__(16) unsigned short Ps[4][16 * 72];

    const int t = threadIdx.x, w = t >> 6, l = t & 63;
    const int qi = blockIdx.x, h = blockIdx.y, b = blockIdx.z;
    const int g = l >> 4, c = l & 15;

    unsigned mask = 1u | (1u << (NB - 1)) | (1u << qi);
    if (qi > 0) mask |= 1u << (qi - 1);
    if (qi < NB - 1) mask |= 1u << (qi + 1);
#pragma unroll
    for (int tt = 0; tt < 3; ++tt)
        if (srcb[tt] == qi) mask |= 1u << (tgtb[tt] & 31);

    const size_t ho = (size_t)(b * 16 + h) * (SEQ * 64);
    const unsigned short* Q = qb_ + ho;
    const unsigned short* K = kb_ + ho;
    const unsigned short* V = vb_ + ho;

    short8 qf[2];
    {
        const unsigned short* qrow = Q + (size_t)(qi * 64 + w * 16 + c) * 64;
        qf[0] = *(const short8*)(qrow + g * 8);
        qf[1] = *(const short8*)(qrow + 32 + g * 8);
    }

    f32x4 oacc[4];
#pragma unroll
    for (int d = 0; d < 4; ++d) oacc[d] = f32x4{0.f, 0.f, 0.f, 0.f};
    float mrun = -INFINITY, lsum = 0.f;

    const int sr = t >> 2, sc = (t & 3) * 16;

    uint4 k0, k1, v0, v1;
    {
        const unsigned short* ksrc = K + (size_t)(0 * 64 + sr) * 64 + sc;
        const unsigned short* vsrc = V + (size_t)(0 * 64 + sr) * 64 + sc;
        k0 = *(const uint4*)ksrc; k1 = *(const uint4*)(ksrc + 8);
        v0 = *(const uint4*)vsrc; v1 = *(const uint4*)(vsrc + 8);
    }

    int kb = 0;
    while (kb < NB) {
        int nxt = kb + 1;
        while (nxt < NB && !((mask >> nxt) & 1u)) ++nxt;

        __syncthreads();
        *(uint4*)&Ks[sr * 72 + sc] = k0;
        *(uint4*)&Ks[sr * 72 + sc + 8] = k1;
        {   // transpose-on-write: Vs[d][key] = V[key][d]
            const unsigned short* p0 = (const unsigned short*)&v0;
            const unsigned short* p1 = (const unsigned short*)&v1;
#pragma unroll
            for (int e = 0; e < 8; ++e) {
                Vs[(sc + e) * 72 + sr] = p0[e];
                Vs[(sc + 8 + e) * 72 + sr] = p1[e];
            }
        }
        __syncthreads();

        if (nxt < NB) {   // T14: next tile's loads fly under compute
            const unsigned short* ksrc = K + (size_t)(nxt * 64 + sr) * 64 + sc;
            const unsigned short* vsrc = V + (size_t)(nxt * 64 + sr) * 64 + sc;
            k0 = *(const uint4*)ksrc; k1 = *(const uint4*)(ksrc + 8);
            v0 = *(const uint4*)vsrc; v1 = *(const uint4*)(vsrc + 8);
        }

        f32x4 sacc[4];
#pragma unroll
        for (int kt = 0; kt < 4; ++kt) sacc[kt] = f32x4{0.f, 0.f, 0.f, 0.f};
#pragma unroll
        for (int kt = 0; kt < 4; ++kt) {
#pragma unroll
            for (int ks = 0; ks < 2; ++ks) {
                const short8 ka = *(const short8*)&Ks[(kt * 16 + c) * 72 + ks * 32 + g * 8];
                sacc[kt] = __builtin_amdgcn_mfma_f32_16x16x32_bf16(ka, qf[ks], sacc[kt], 0, 0, 0);
            }
        }

        float sv[16];
        float tmax = -INFINITY;
#pragma unroll
        for (int kt = 0; kt < 4; ++kt)
#pragma unroll
            for (int j = 0; j < 4; ++j) {
                const float x = sacc[kt][j] * 0.125f;
                sv[kt * 4 + j] = x;
                tmax = fmaxf(tmax, x);
            }
        tmax = fmaxf(tmax, __shfl_xor(tmax, 16));
        tmax = fmaxf(tmax, __shfl_xor(tmax, 32));
        const float newm = fmaxf(mrun, tmax);
        const float corr = __expf(mrun - newm);
        float ps = 0.f;
#pragma unroll
        for (int e = 0; e < 16; ++e) {
            const float p = __expf(sv[e] - newm);
            sv[e] = p;
            ps += p;
        }
        ps += __shfl_xor(ps, 16);
        ps += __shfl_xor(ps, 32);
        lsum = lsum * corr + ps;
        mrun = newm;
#pragma unroll
        for (int d = 0; d < 4; ++d)
#pragma unroll
            for (int j = 0; j < 4; ++j) oacc[d][j] *= corr;

        unsigned short* pw = &Ps[w][c * 72];
#pragma unroll
        for (int kt = 0; kt < 4; ++kt) {
            uint2 pk;
            pk.x = f2bf(sv[kt * 4 + 0]) | ((unsigned)f2bf(sv[kt * 4 + 1]) << 16);
            pk.y = f2bf(sv[kt * 4 + 2]) | ((unsigned)f2bf(sv[kt * 4 + 3]) << 16);
            *(uint2*)&pw[kt * 16 + g * 4] = pk;
        }
        asm volatile("s_waitcnt lgkmcnt(0)" ::: "memory");   // same-wave LDS RAW
        __builtin_amdgcn_sched_barrier(0);

#pragma unroll
        for (int ks = 0; ks < 2; ++ks) {
            const short8 pb = *(const short8*)&Ps[w][c * 72 + ks * 32 + g * 8];
#pragma unroll
            for (int dt = 0; dt < 4; ++dt) {
                const short8 va = *(const short8*)&Vs[(dt * 16 + c) * 72 + ks * 32 + g * 8];
                oacc[dt] = __builtin_amdgcn_mfma_f32_16x16x32_bf16(va, pb, oacc[dt], 0, 0, 0);
            }
        }

        kb = nxt;
    }

    const float inv = 1.f / lsum;
    unsigned short* orow = outb + (size_t)(b * SEQ + qi * 64 + w * 16 + c) * 1024 + h * 64;
#pragma unroll
    for (int dt = 0; dt < 4; ++dt)
#pragma unroll
        for (int j = 0; j < 4; ++j)
            orow[dt * 16 + g * 4 + j] = f2bf(oacc[dt][j] * inv);
}

// ---------------------------------------------------------------------------
extern "C" void kernel_launch(void* const* d_in, const int* in_sizes, int n_in,
                              void* d_out, int out_size, void* d_ws, size_t ws_size,
                              hipStream_t stream) {
    const float* x  = (const float*)d_in[0];
    const float* Wq = (const float*)d_in[1];
    const float* bq = (const float*)d_in[2];
    const float* Wk = (const float*)d_in[3];
    const float* bk = (const float*)d_in[4];
    const float* Wv = (const float*)d_in[5];
    const float* bv = (const float*)d_in[6];
    const float* Wo = (const float*)d_in[7];
    const float* bo = (const float*)d_in[8];
    const int* srcb = (const int*)d_in[9];
    const int* tgtb = (const int*)d_in[10];

    unsigned short* wsu = (unsigned short*)d_ws;
    unsigned short* xbf   = wsu;                      // [0,        4194304)
    unsigned short* wqkv  = wsu + 4194304ull;         // [4194304,  7340032)
    unsigned short* wobf  = wsu + 7340032ull;         // [7340032,  8388608)
    unsigned short* qkvbf = wsu + 8388608ull;         // [8388608,  20971520) Q,K,V panes
    unsigned short* attbf = wsu + 25165824ull;        // [25165824, 29360128)

    // zero d_out: split-K atomics accumulate into it (also replay-safe)
    hipMemsetAsync(d_out, 0, (size_t)out_size * sizeof(float), stream);

    hipLaunchKernelGGL(cvt_all, dim3(512, 5), dim3(256), 0, stream,
                       x, Wq, Wk, Wv, Wo,
                       xbf, wqkv, wqkv + 1048576ull, wqkv + 2097152ull, wobf);

    // fused QKV GEMM (frozen round-11 structure: BM=128, 768 wgs)
    hipLaunchKernelGGL((gemm_bt<1, 128>), dim3(24, 32), dim3(256), 0, stream,
                       xbf, wqkv, bq, bk, bv, qkvbf, (float*)nullptr);

    // attention (V transposed in-kernel; T14 async-stage prefetch)
    hipLaunchKernelGGL(attn_mfma, dim3(32, 16, 2), dim3(256), 0, stream,
                       qkvbf, qkvbf + 4194304ull, qkvbf + 2ull * 4194304ull,
                       srcb, tgtb, attbf);

    // O projection -> fp32 d_out (split-K=2, BK=64, swizzled, atomic)
    hipLaunchKernelGGL(gemm_obt_sk, dim3(16, 32, 2), dim3(256), 0, stream,
                       attbf, wobf, bo, (float*)d_out);

    (void)in_sizes; (void)n_in; (void)out_size; (void)ws_size;
}

// Round 18
// 92.175 us; speedup vs baseline: 1.2119x; 1.2119x over previous
//
#include <hip/hip_runtime.h>
#include <math.h>

typedef __attribute__((ext_vector_type(8))) short short8;
typedef __attribute__((ext_vector_type(4))) float f32x4;

#define SEQ 2048
#define NB  32

__device__ __forceinline__ unsigned short f2bf(float f) {
    unsigned u = __float_as_uint(f);
    u = (u + 0x7FFFu + ((u >> 16) & 1u)) >> 16;   // RNE
    return (unsigned short)u;
}

// async global->LDS, 16B per lane; LDS dest = wave-uniform base + lane*16
__device__ __forceinline__ void gload16(const unsigned short* g, unsigned short* l) {
    __builtin_amdgcn_global_load_lds(
        (__attribute__((address_space(1))) void*)(void*)(g),
        (__attribute__((address_space(3))) void*)(l), 16, 0, 0);
}

// ---------------------------------------------------------------------------
// fp32 -> bf16 (RNE): 5 tensors in ONE dispatch. blockIdx.y selects the job.
// ---------------------------------------------------------------------------
__global__ __launch_bounds__(256) void cvt_all(const float* __restrict__ x,
                                               const float* __restrict__ w0,
                                               const float* __restrict__ w1,
                                               const float* __restrict__ w2,
                                               const float* __restrict__ w3,
                                               unsigned short* __restrict__ ox,
                                               unsigned short* __restrict__ o0,
                                               unsigned short* __restrict__ o1,
                                               unsigned short* __restrict__ o2,
                                               unsigned short* __restrict__ o3) {
    const int which = blockIdx.y;
    const float* in = (which == 0) ? x : (which == 1) ? w0 : (which == 2) ? w1
                       : (which == 3) ? w2 : w3;
    unsigned short* out = (which == 0) ? ox : (which == 1) ? o0 : (which == 2) ? o1
                          : (which == 3) ? o2 : o3;
    const int n8 = (which == 0) ? 524288 : 131072;
    int i = blockIdx.x * 256 + threadIdx.x;
    const int stride = gridDim.x * 256;
    for (; i < n8; i += stride) {
        const float4 a = ((const float4*)in)[i * 2];
        const float4 b = ((const float4*)in)[i * 2 + 1];
        uint4 o;
        o.x = f2bf(a.x) | ((unsigned)f2bf(a.y) << 16);
        o.y = f2bf(a.z) | ((unsigned)f2bf(a.w) << 16);
        o.z = f2bf(b.x) | ((unsigned)f2bf(b.y) << 16);
        o.w = f2bf(b.z) | ((unsigned)f2bf(b.w) << 16);
        ((uint4*)out)[i] = o;
    }
}

// ---------------------------------------------------------------------------
// QKV bf16 MFMA GEMM — PERMANENTLY FROZEN (round-11/15 structure, 43.6us,
// 592 TF = the 2-phase family floor per m233). Do not touch.
// BN=128: 4 waves 2x2 (64x64, MI=4), grid (24, 32), which=bx>>3.
// NOTE (round-3 lesson): head split is a .view — head h = GEMM ROWS.
// ---------------------------------------------------------------------------
template <int BF16OUT, int BN>
__global__ __launch_bounds__(256) void gemm_bt(const unsigned short* __restrict__ A,
                                               const unsigned short* __restrict__ Wall,
                                               const float* __restrict__ b0,
                                               const float* __restrict__ b1,
                                               const float* __restrict__ b2,
                                               unsigned short* __restrict__ outb,
                                               float* __restrict__ outf) {
    constexpr int MI = (BN == 128) ? 4 : 2;
    constexpr int NI = 4;
    __shared__ __align__(16) unsigned short SMEM[2 * 128 * 32 + 2 * BN * 32];
    unsigned short* As0 = SMEM;
    unsigned short* As1 = SMEM + 128 * 32;
    unsigned short* Bs0 = SMEM + 2 * 128 * 32;
    unsigned short* Bs1 = SMEM + 2 * 128 * 32 + BN * 32;

    const int t = threadIdx.x;
    const int w = t >> 6, l = t & 63;
    const int bx = blockIdx.x;
    const int which = (BN == 128) ? (bx >> 3) : 0;
    const int n0 = (BN == 128) ? (bx & 7) * 128 : bx * 64;
    const int m0 = blockIdx.y * 128;
    const unsigned short* W = Wall + (size_t)which * (1024ull * 1024);
    const float* bias = (which == 0) ? b0 : (which == 1) ? b1 : b2;

    const int wr = (BN == 128) ? (w >> 1) * 64 : w * 32;
    const int wc = (BN == 128) ? (w & 1) * 64 : 0;

    f32x4 acc[MI][NI];
#pragma unroll
    for (int i = 0; i < MI; ++i)
#pragma unroll
        for (int j = 0; j < NI; ++j) acc[i][j] = f32x4{0.f, 0.f, 0.f, 0.f};

    const unsigned short* Ag = A + (size_t)(m0 + w * 32 + (l >> 2)) * 1024 + (l & 3) * 8;
    const unsigned short* Wg =
        W + (size_t)(n0 + ((BN == 128) ? w * 32 : w * 16) + (l >> 2)) * 1024 + (l & 3) * 8;

    auto STAGE = [&](unsigned short* Asb, unsigned short* Bsb, int k0) {
        gload16(Ag + k0, Asb + w * 1024);
        gload16(Ag + k0 + 16 * 1024, Asb + w * 1024 + 512);
        gload16(Wg + k0, Bsb + ((BN == 128) ? w * 1024 : w * 512));
        if (BN == 128) gload16(Wg + k0 + 16 * 1024, Bsb + w * 1024 + 512);
    };
    auto COMPUTE = [&](const unsigned short* Asb, const unsigned short* Bsb) {
        short8 af[MI], bfr[NI];
#pragma unroll
        for (int mi = 0; mi < MI; ++mi)
            af[mi] = *(const short8*)&Asb[(wr + mi * 16 + (l & 15)) * 32 + (l >> 4) * 8];
#pragma unroll
        for (int ni = 0; ni < NI; ++ni)
            bfr[ni] = *(const short8*)&Bsb[(wc + ni * 16 + (l & 15)) * 32 + (l >> 4) * 8];
#pragma unroll
        for (int mi = 0; mi < MI; ++mi)
#pragma unroll
            for (int ni = 0; ni < NI; ++ni)
                acc[mi][ni] = __builtin_amdgcn_mfma_f32_16x16x32_bf16(af[mi], bfr[ni],
                                                                      acc[mi][ni], 0, 0, 0);
    };
#define WAITV_INFLIGHT()                                                  \
    do {                                                                  \
        if constexpr (BN == 128)                                          \
            asm volatile("s_waitcnt vmcnt(4)" ::: "memory");              \
        else                                                              \
            asm volatile("s_waitcnt vmcnt(3)" ::: "memory");              \
        __builtin_amdgcn_sched_barrier(0);                                \
    } while (0)
#define BAR()                                                             \
    do {                                                                  \
        __builtin_amdgcn_s_barrier();                                     \
        __builtin_amdgcn_sched_barrier(0);                                \
    } while (0)
#define READS_DONE_BAR()                                                  \
    do {                                                                  \
        asm volatile("s_waitcnt lgkmcnt(0)" ::: "memory");                \
        __builtin_amdgcn_sched_barrier(0);                                \
        __builtin_amdgcn_s_barrier();                                     \
        __builtin_amdgcn_sched_barrier(0);                                \
    } while (0)

    STAGE(As0, Bs0, 0);
#pragma unroll 1
    for (int kt2 = 0; kt2 < 16; ++kt2) {
        STAGE(As1, Bs1, (kt2 * 2 + 1) * 32);
        WAITV_INFLIGHT();
        BAR();
        COMPUTE(As0, Bs0);
        READS_DONE_BAR();

        if (kt2 < 15) {
            STAGE(As0, Bs0, (kt2 * 2 + 2) * 32);
            WAITV_INFLIGHT();
        } else {
            asm volatile("s_waitcnt vmcnt(0)" ::: "memory");
            __builtin_amdgcn_sched_barrier(0);
        }
        BAR();
        COMPUTE(As1, Bs1);
        if (kt2 < 15) READS_DONE_BAR();
    }
#undef WAITV_INFLIGHT
#undef BAR
#undef READS_DONE_BAR

    __syncthreads();
    const int g = l >> 4, c = l & 15;
    if constexpr (BF16OUT) {
        unsigned short* eb = SMEM + w * (32 * 72);
        unsigned short* outw = outb + (size_t)which * (4096ull * 1024);
        const int r1 = l >> 1, hh = (l & 1) * 32;
#pragma unroll
        for (int half = 0; half < 2; ++half) {
#pragma unroll
            for (int ni = 0; ni < NI; ++ni) {
                const float bv = bias[n0 + wc + ni * 16 + c];
#pragma unroll
                for (int mi2 = 0; mi2 < 2; ++mi2)
#pragma unroll
                    for (int j = 0; j < 4; ++j)
                        eb[(mi2 * 16 + g * 4 + j) * 72 + ni * 16 + c] =
                            f2bf(acc[half * 2 + mi2][ni][j] + bv);
            }
            asm volatile("s_waitcnt lgkmcnt(0)" ::: "memory");
            __builtin_amdgcn_sched_barrier(0);
            const unsigned short* src = eb + r1 * 72 + hh;
            unsigned short* dst =
                &outw[(size_t)(m0 + wr + half * 32 + r1) * 1024 + n0 + wc + hh];
#pragma unroll
            for (int q = 0; q < 4; ++q)
                *(uint4*)(dst + q * 8) = *(const uint4*)(src + q * 8);
            asm volatile("s_waitcnt lgkmcnt(0)" ::: "memory");
            __builtin_amdgcn_sched_barrier(0);
        }
    } else {
        float* ef = (float*)SMEM + w * (16 * 68);
        const int r2 = l >> 2, qq = (l & 3) * 16;
#pragma unroll
        for (int mi = 0; mi < MI; ++mi) {
#pragma unroll
            for (int ni = 0; ni < NI; ++ni) {
                const float bv = bias[n0 + wc + ni * 16 + c];
#pragma unroll
                for (int j = 0; j < 4; ++j)
                    ef[(g * 4 + j) * 68 + ni * 16 + c] = acc[mi][ni][j] + bv;
            }
            asm volatile("s_waitcnt lgkmcnt(0)" ::: "memory");
            __builtin_amdgcn_sched_barrier(0);
            const float* srcf = ef + r2 * 68 + qq;
            float* dstf = &outf[(size_t)(m0 + wr + mi * 16 + r2) * 1024 + n0 + wc + qq];
#pragma unroll
            for (int q = 0; q < 4; ++q)
                *(float4*)(dstf + q * 4) = *(const float4*)(srcf + q * 4);
            asm volatile("s_waitcnt lgkmcnt(0)" ::: "memory");
            __builtin_amdgcn_sched_barrier(0);
        }
    }
}

// ---------------------------------------------------------------------------
// O-projection GEMM — round-16 config (session best): BK=64, 16 K-steps,
// T2 XOR-swizzle via pre-swizzled global source (m173), plain coalesced
// LDS-staged fp32 epilogue. (Round-17 split-K+atomics refuted: +19us from
// 33.5M dword RMW atomics + 16.8MB memset dispatch.)
// BM=128, BN=64, grid (16,32)=512 wgs. 4 waves, each 32x64 (MI=2,NI=4,kk=2).
// ---------------------------------------------------------------------------
__global__ __launch_bounds__(256) void gemm_obt(const unsigned short* __restrict__ A,
                                                const unsigned short* __restrict__ W,
                                                const float* __restrict__ bias,
                                                float* __restrict__ outf) {
    constexpr int MI = 2, NI = 4;
    __shared__ __align__(16) unsigned short SMEM[2 * (128 + 64) * 64];
    unsigned short* As0 = SMEM;                    // [128][64]
    unsigned short* As1 = SMEM + 128 * 64;
    unsigned short* Bs0 = SMEM + 2 * 128 * 64;     // [64][64]
    unsigned short* Bs1 = SMEM + 2 * 128 * 64 + 64 * 64;

    const int t = threadIdx.x;
    const int w = t >> 6, l = t & 63;
    const int n0 = blockIdx.x * 64;
    const int m0 = blockIdx.y * 128;

    const int wr = w * 32, wc = 0;

    f32x4 acc[MI][NI];
#pragma unroll
    for (int i = 0; i < MI; ++i)
#pragma unroll
        for (int j = 0; j < NI; ++j) acc[i][j] = f32x4{0.f, 0.f, 0.f, 0.f};

    // staging: lane l covers row (l>>3), global col-short ((l&7)^(l>>3))*8
    const int scol = ((l & 7) ^ (l >> 3)) * 8;
    const unsigned short* Ag = A + (size_t)(m0 + w * 32 + (l >> 3)) * 1024 + scol;
    const unsigned short* Wg = W + (size_t)(n0 + w * 16 + (l >> 3)) * 1024 + scol;

    auto STAGE = [&](unsigned short* Asb, unsigned short* Bsb, int k0) {
        gload16(Ag + k0, Asb + (w * 32) * 64);
        gload16(Ag + k0 + 8 * 1024, Asb + (w * 32 + 8) * 64);
        gload16(Ag + k0 + 16 * 1024, Asb + (w * 32 + 16) * 64);
        gload16(Ag + k0 + 24 * 1024, Asb + (w * 32 + 24) * 64);
        gload16(Wg + k0, Bsb + (w * 16) * 64);
        gload16(Wg + k0 + 8 * 1024, Bsb + (w * 16 + 8) * 64);
    };
    auto COMPUTE = [&](const unsigned short* Asb, const unsigned short* Bsb) {
#pragma unroll
        for (int kk = 0; kk < 2; ++kk) {
            short8 af[MI], bfr[NI];
#pragma unroll
            for (int mi = 0; mi < MI; ++mi) {
                const int r = wr + mi * 16 + (l & 15);
                const int slot = (kk * 4 + (l >> 4)) ^ (r & 7);
                af[mi] = *(const short8*)&Asb[r * 64 + slot * 8];
            }
#pragma unroll
            for (int ni = 0; ni < NI; ++ni) {
                const int r = wc + ni * 16 + (l & 15);
                const int slot = (kk * 4 + (l >> 4)) ^ (r & 7);
                bfr[ni] = *(const short8*)&Bsb[r * 64 + slot * 8];
            }
#pragma unroll
            for (int mi = 0; mi < MI; ++mi)
#pragma unroll
                for (int ni = 0; ni < NI; ++ni)
                    acc[mi][ni] = __builtin_amdgcn_mfma_f32_16x16x32_bf16(
                        af[mi], bfr[ni], acc[mi][ni], 0, 0, 0);
        }
    };
#define WV6()                                                             \
    do {                                                                  \
        asm volatile("s_waitcnt vmcnt(6)" ::: "memory");                  \
        __builtin_amdgcn_sched_barrier(0);                                \
    } while (0)
#define BAR()                                                             \
    do {                                                                  \
        __builtin_amdgcn_s_barrier();                                     \
        __builtin_amdgcn_sched_barrier(0);                                \
    } while (0)
#define READS_DONE_BAR()                                                  \
    do {                                                                  \
        asm volatile("s_waitcnt lgkmcnt(0)" ::: "memory");                \
        __builtin_amdgcn_sched_barrier(0);                                \
        __builtin_amdgcn_s_barrier();                                     \
        __builtin_amdgcn_sched_barrier(0);                                \
    } while (0)

    STAGE(As0, Bs0, 0);
#pragma unroll 1
    for (int kt2 = 0; kt2 < 8; ++kt2) {          // 16 K-steps of 64
        STAGE(As1, Bs1, (kt2 * 2 + 1) * 64);
        WV6();
        BAR();
        COMPUTE(As0, Bs0);
        READS_DONE_BAR();

        if (kt2 < 7) {
            STAGE(As0, Bs0, (kt2 * 2 + 2) * 64);
            WV6();
        } else {
            asm volatile("s_waitcnt vmcnt(0)" ::: "memory");
            __builtin_amdgcn_sched_barrier(0);
        }
        BAR();
        COMPUTE(As1, Bs1);
        if (kt2 < 7) READS_DONE_BAR();
    }
#undef WV6
#undef BAR
#undef READS_DONE_BAR

    // fp32 coalesced epilogue via LDS
    __syncthreads();
    const int g = l >> 4, c = l & 15;
    float* ef = (float*)SMEM + w * (16 * 68);
    const int r2 = l >> 2, qq = (l & 3) * 16;
#pragma unroll
    for (int mi = 0; mi < MI; ++mi) {
#pragma unroll
        for (int ni = 0; ni < NI; ++ni) {
            const float bv = bias[n0 + wc + ni * 16 + c];
#pragma unroll
            for (int j = 0; j < 4; ++j)
                ef[(g * 4 + j) * 68 + ni * 16 + c] = acc[mi][ni][j] + bv;
        }
        asm volatile("s_waitcnt lgkmcnt(0)" ::: "memory");
        __builtin_amdgcn_sched_barrier(0);
        const float* srcf = ef + r2 * 68 + qq;
        float* dstf = &outf[(size_t)(m0 + wr + mi * 16 + r2) * 1024 + n0 + wc + qq];
#pragma unroll
        for (int q = 0; q < 4; ++q)
            *(float4*)(dstf + q * 4) = *(const float4*)(srcf + q * 4);
        asm volatile("s_waitcnt lgkmcnt(0)" ::: "memory");
        __builtin_amdgcn_sched_barrier(0);
    }
}

// ---------------------------------------------------------------------------
// BigBird MFMA attention (bf16 in, bf16 out), swapped-QK^T flash style.
// grid (32 qblk, 16 h, 2 b), 256 thr = 4 waves; wave w owns 16 q-rows.
// S^T = K·Q^T -> softmax in-lane + 2 shfl_xor;  O^T = V^T·P^T.
// V transposed during LDS staging; T14 prefetch-next-active-block (round-15).
// ---------------------------------------------------------------------------
__global__ __launch_bounds__(256) void attn_mfma(const unsigned short* __restrict__ qb_,
                                                 const unsigned short* __restrict__ kb_,
                                                 const unsigned short* __restrict__ vb_,
                                                 const int* __restrict__ srcb,
                                                 const int* __restrict__ tgtb,
                                                 unsigned short* __restrict__ outb) {
    __shared__ __align__(16) unsigned short Ks[64 * 72];
    __shared__ __align__(16) unsigned short Vs[64 * 72];   // V^T tile [d][key]
    __shared__ __align__(16) unsigned short Ps[4][16 * 72];

    const int t = threadIdx.x, w = t >> 6, l = t & 63;
    const int qi = blockIdx.x, h = blockIdx.y, b = blockIdx.z;
    const int g = l >> 4, c = l & 15;

    unsigned mask = 1u | (1u << (NB - 1)) | (1u << qi);
    if (qi > 0) mask |= 1u << (qi - 1);
    if (qi < NB - 1) mask |= 1u << (qi + 1);
#pragma unroll
    for (int tt = 0; tt < 3; ++tt)
        if (srcb[tt] == qi) mask |= 1u << (tgtb[tt] & 31);

    const size_t ho = (size_t)(b * 16 + h) * (SEQ * 64);
    const unsigned short* Q = qb_ + ho;
    const unsigned short* K = kb_ + ho;
    const unsigned short* V = vb_ + ho;

    short8 qf[2];
    {
        const unsigned short* qrow = Q + (size_t)(qi * 64 + w * 16 + c) * 64;
        qf[0] = *(const short8*)(qrow + g * 8);
        qf[1] = *(const short8*)(qrow + 32 + g * 8);
    }

    f32x4 oacc[4];
#pragma unroll
    for (int d = 0; d < 4; ++d) oacc[d] = f32x4{0.f, 0.f, 0.f, 0.f};
    float mrun = -INFINITY, lsum = 0.f;

    const int sr = t >> 2, sc = (t & 3) * 16;

    uint4 k0, k1, v0, v1;
    {
        const unsigned short* ksrc = K + (size_t)(0 * 64 + sr) * 64 + sc;
        const unsigned short* vsrc = V + (size_t)(0 * 64 + sr) * 64 + sc;
        k0 = *(const uint4*)ksrc; k1 = *(const uint4*)(ksrc + 8);
        v0 = *(const uint4*)vsrc; v1 = *(const uint4*)(vsrc + 8);
    }

    int kb = 0;
    while (kb < NB) {
        int nxt = kb + 1;
        while (nxt < NB && !((mask >> nxt) & 1u)) ++nxt;

        __syncthreads();
        *(uint4*)&Ks[sr * 72 + sc] = k0;
        *(uint4*)&Ks[sr * 72 + sc + 8] = k1;
        {   // transpose-on-write: Vs[d][key] = V[key][d]
            const unsigned short* p0 = (const unsigned short*)&v0;
            const unsigned short* p1 = (const unsigned short*)&v1;
#pragma unroll
            for (int e = 0; e < 8; ++e) {
                Vs[(sc + e) * 72 + sr] = p0[e];
                Vs[(sc + 8 + e) * 72 + sr] = p1[e];
            }
        }
        __syncthreads();

        if (nxt < NB) {   // T14: next tile's loads fly under compute
            const unsigned short* ksrc = K + (size_t)(nxt * 64 + sr) * 64 + sc;
            const unsigned short* vsrc = V + (size_t)(nxt * 64 + sr) * 64 + sc;
            k0 = *(const uint4*)ksrc; k1 = *(const uint4*)(ksrc + 8);
            v0 = *(const uint4*)vsrc; v1 = *(const uint4*)(vsrc + 8);
        }

        f32x4 sacc[4];
#pragma unroll
        for (int kt = 0; kt < 4; ++kt) sacc[kt] = f32x4{0.f, 0.f, 0.f, 0.f};
#pragma unroll
        for (int kt = 0; kt < 4; ++kt) {
#pragma unroll
            for (int ks = 0; ks < 2; ++ks) {
                const short8 ka = *(const short8*)&Ks[(kt * 16 + c) * 72 + ks * 32 + g * 8];
                sacc[kt] = __builtin_amdgcn_mfma_f32_16x16x32_bf16(ka, qf[ks], sacc[kt], 0, 0, 0);
            }
        }

        float sv[16];
        float tmax = -INFINITY;
#pragma unroll
        for (int kt = 0; kt < 4; ++kt)
#pragma unroll
            for (int j = 0; j < 4; ++j) {
                const float x = sacc[kt][j] * 0.125f;
                sv[kt * 4 + j] = x;
                tmax = fmaxf(tmax, x);
            }
        tmax = fmaxf(tmax, __shfl_xor(tmax, 16));
        tmax = fmaxf(tmax, __shfl_xor(tmax, 32));
        const float newm = fmaxf(mrun, tmax);
        const float corr = __expf(mrun - newm);
        float ps = 0.f;
#pragma unroll
        for (int e = 0; e < 16; ++e) {
            const float p = __expf(sv[e] - newm);
            sv[e] = p;
            ps += p;
        }
        ps += __shfl_xor(ps, 16);
        ps += __shfl_xor(ps, 32);
        lsum = lsum * corr + ps;
        mrun = newm;
#pragma unroll
        for (int d = 0; d < 4; ++d)
#pragma unroll
            for (int j = 0; j < 4; ++j) oacc[d][j] *= corr;

        unsigned short* pw = &Ps[w][c * 72];
#pragma unroll
        for (int kt = 0; kt < 4; ++kt) {
            uint2 pk;
            pk.x = f2bf(sv[kt * 4 + 0]) | ((unsigned)f2bf(sv[kt * 4 + 1]) << 16);
            pk.y = f2bf(sv[kt * 4 + 2]) | ((unsigned)f2bf(sv[kt * 4 + 3]) << 16);
            *(uint2*)&pw[kt * 16 + g * 4] = pk;
        }
        asm volatile("s_waitcnt lgkmcnt(0)" ::: "memory");   // same-wave LDS RAW
        __builtin_amdgcn_sched_barrier(0);

#pragma unroll
        for (int ks = 0; ks < 2; ++ks) {
            const short8 pb = *(const short8*)&Ps[w][c * 72 + ks * 32 + g * 8];
#pragma unroll
            for (int dt = 0; dt < 4; ++dt) {
                const short8 va = *(const short8*)&Vs[(dt * 16 + c) * 72 + ks * 32 + g * 8];
                oacc[dt] = __builtin_amdgcn_mfma_f32_16x16x32_bf16(va, pb, oacc[dt], 0, 0, 0);
            }
        }

        kb = nxt;
    }

    const float inv = 1.f / lsum;
    unsigned short* orow = outb + (size_t)(b * SEQ + qi * 64 + w * 16 + c) * 1024 + h * 64;
#pragma unroll
    for (int dt = 0; dt < 4; ++dt)
#pragma unroll
        for (int j = 0; j < 4; ++j)
            orow[dt * 16 + g * 4 + j] = f2bf(oacc[dt][j] * inv);
}

// ---------------------------------------------------------------------------
extern "C" void kernel_launch(void* const* d_in, const int* in_sizes, int n_in,
                              void* d_out, int out_size, void* d_ws, size_t ws_size,
                              hipStream_t stream) {
    const float* x  = (const float*)d_in[0];
    const float* Wq = (const float*)d_in[1];
    const float* bq = (const float*)d_in[2];
    const float* Wk = (const float*)d_in[3];
    const float* bk = (const float*)d_in[4];
    const float* Wv = (const float*)d_in[5];
    const float* bv = (const float*)d_in[6];
    const float* Wo = (const float*)d_in[7];
    const float* bo = (const float*)d_in[8];
    const int* srcb = (const int*)d_in[9];
    const int* tgtb = (const int*)d_in[10];

    unsigned short* wsu = (unsigned short*)d_ws;
    unsigned short* xbf   = wsu;                      // [0,        4194304)
    unsigned short* wqkv  = wsu + 4194304ull;         // [4194304,  7340032)
    unsigned short* wobf  = wsu + 7340032ull;         // [7340032,  8388608)
    unsigned short* qkvbf = wsu + 8388608ull;         // [8388608,  20971520) Q,K,V panes
    unsigned short* attbf = wsu + 25165824ull;        // [25165824, 29360128)

    hipLaunchKernelGGL(cvt_all, dim3(512, 5), dim3(256), 0, stream,
                       x, Wq, Wk, Wv, Wo,
                       xbf, wqkv, wqkv + 1048576ull, wqkv + 2097152ull, wobf);

    // fused QKV GEMM (frozen round-11 structure: BM=128, 768 wgs)
    hipLaunchKernelGGL((gemm_bt<1, 128>), dim3(24, 32), dim3(256), 0, stream,
                       xbf, wqkv, bq, bk, bv, qkvbf, (float*)nullptr);

    // attention (V transposed in-kernel; T14 async-stage prefetch)
    hipLaunchKernelGGL(attn_mfma, dim3(32, 16, 2), dim3(256), 0, stream,
                       qkvbf, qkvbf + 4194304ull, qkvbf + 2ull * 4194304ull,
                       srcb, tgtb, attbf);

    // O projection -> fp32 d_out (BK=64, 16 steps, swizzled LDS)
    hipLaunchKernelGGL(gemm_obt, dim3(16, 32), dim3(256), 0, stream,
                       attbf, wobf, bo, (float*)d_out);

    (void)in_sizes; (void)n_in; (void)out_size; (void)ws_size;
}